// Round 16
// baseline (145.969 us; speedup 1.0000x reference)
//
#include <hip/hip_runtime.h>
#include <hip/hip_bf16.h>

typedef __attribute__((ext_vector_type(8))) short bf16x8;
typedef __attribute__((ext_vector_type(4))) float f32x4;

__device__ __forceinline__ short f2b(float x) {
    __hip_bfloat16 h = __float2bfloat16(x);
    short s;
    __builtin_memcpy(&s, &h, 2);
    return s;
}

__device__ __forceinline__ void gload16(const short* g, const short* l) {
    __builtin_amdgcn_global_load_lds((const __attribute__((address_space(1))) void*)g,
                                     (__attribute__((address_space(3))) void*)l, 16, 0, 0);
}

// raw 2^x: v_exp_f32 with no libm fixups (r12: exp2f() libm slow path cost 13us).
__device__ __forceinline__ float fexp2(float x) {
#if __has_builtin(__builtin_amdgcn_exp2f)
    return __builtin_amdgcn_exp2f(x);
#else
    return __expf(x * 0.69314718056f);
#endif
}

// ---------------- prep: W fp32->bf16 converts + memory rows/pads ----------------
__global__ __launch_bounds__(256) void k_prep(const float* __restrict__ Wq,
                                              const float* __restrict__ Wk,
                                              const float* __restrict__ Wv,
                                              const float* __restrict__ Wo,
                                              const float* __restrict__ mk,
                                              const float* __restrict__ mv,
                                              short* __restrict__ dst,    // = Wqb (base of W bf16 region)
                                              short* __restrict__ kcat,
                                              short* __restrict__ vcat,
                                              short* __restrict__ vt) {
    const int y = blockIdx.y;
    const int i0 = blockIdx.x * 256 + threadIdx.x;
    if (y < 4) {
        const float* src = (y == 0) ? Wq : (y == 1) ? Wk : (y == 2) ? Wv : Wo;
        float4 val = ((const float4*)src)[i0];
        short4 o;
        o.x = f2b(val.x); o.y = f2b(val.y); o.z = f2b(val.z); o.w = f2b(val.w);
        ((short4*)dst)[(size_t)y * 262144 + i0] = o;
    } else {
        if (i0 < 131072) {
            int b = i0 >> 16;
            int r = (i0 >> 10) & 63;
            int d = i0 & 1023;
            kcat[((size_t)(b * 2176 + 2048 + r)) * 1024 + d] = f2b(mk[r * 1024 + d] * 8.0f);
            vcat[((size_t)(b * 2176 + 2048 + r)) * 1024 + d] = f2b(mv[r * 1024 + d] * 8.0f);
            kcat[((size_t)(b * 2176 + 2112 + r)) * 1024 + d] = 0;
            int h = (i0 >> 12) & 15, dd = (i0 >> 6) & 63, c = i0 & 63;
            vt[((size_t)((b * 16 + h) * 64 + dd)) * 2176 + 2112 + c] = 0;
        }
    }
}

// ---------------- bf16 NT GEMM core, A fp32 with PIPELINED in-staging convert ----------
// r15's serial chain (load->wait->cvt->write->barrier) exposed a full memory
// latency per K-step. r16: A fp32 prefetched one step ahead in registers; the
// loads are issued AFTER barrier2 so their drain lands at the NEXT iteration's
// barrier1, covered by the MFMA phase. cvt+ds_write at loop top uses registers
// that arrived a full iteration ago.
template <int MODE>
__device__ __forceinline__ void gemm_core(const float* __restrict__ A32,
                                          const short* __restrict__ Bw,
                                          const float* __restrict__ bias,
                                          void* __restrict__ Cout,
                                          int bm, int bn,
                                          short (*As)[32], short (*Bs)[32]) {
    const int tid = threadIdx.x;
    const int w = tid >> 6, lane = tid & 63;
    const int wm = w >> 2, wn = w & 3;           // 2 x 4 wave grid
    const int lr = lane & 15, lg = lane >> 4;
    const int srow = tid >> 2;                    // staging row 0..127
    const int c_src = (tid & 3) ^ ((tid >> 3) & 3);
    const int w16 = w * 16;                       // wave-uniform LDS segment base (B)
    const int slot = lg ^ ((lr >> 1) & 3);

    const float* ap = A32 + (size_t)(bm * 128 + srow) * 1024 + c_src * 8;
    const short* Bb = Bw + (size_t)(bn * 128) * 1024;

    // prologue: prefetch A(k0=0) into registers
    float4 a0 = *(const float4*)ap;
    float4 a1 = *(const float4*)(ap + 4);

    f32x4 acc[4][2] = {};

    for (int k0 = 0; k0 < 1024; k0 += 32) {
        __syncthreads();
        gload16(Bb + (size_t)srow * 1024 + k0 + c_src * 8, &Bs[w16][0]);
        bf16x8 apk;
        apk[0] = f2b(a0.x); apk[1] = f2b(a0.y); apk[2] = f2b(a0.z); apk[3] = f2b(a0.w);
        apk[4] = f2b(a1.x); apk[5] = f2b(a1.y); apk[6] = f2b(a1.z); apk[7] = f2b(a1.w);
        *(bf16x8*)((char*)&As[0][0] + srow * 64 + (tid & 3) * 16) = apk;
        __syncthreads();
        // issue next step's A loads here: latency hides under the MFMA phase,
        // drained at the next iteration's first barrier.
        if (k0 < 992) {
            const float* apn = ap + k0 + 32;
            a0 = *(const float4*)apn;
            a1 = *(const float4*)(apn + 4);
        }
        bf16x8 af[4], bfr[2];
        #pragma unroll
        for (int m = 0; m < 4; ++m) {
            int row = wm * 64 + m * 16 + lr;
            af[m] = *(const bf16x8*)((const char*)As + row * 64 + slot * 16);
        }
        #pragma unroll
        for (int n = 0; n < 2; ++n) {
            int row = wn * 32 + n * 16 + lr;
            bfr[n] = *(const bf16x8*)((const char*)Bs + row * 64 + slot * 16);
        }
        #pragma unroll
        for (int m = 0; m < 4; ++m)
            #pragma unroll
            for (int n = 0; n < 2; ++n)
                acc[m][n] = __builtin_amdgcn_mfma_f32_16x16x32_bf16(af[m], bfr[n], acc[m][n], 0, 0, 0);
    }

    #pragma unroll
    for (int m = 0; m < 4; ++m) {
        #pragma unroll
        for (int n = 0; n < 2; ++n) {
            int col = bn * 128 + wn * 32 + n * 16 + lr;
            float bv = bias[col];
            #pragma unroll
            for (int r = 0; r < 4; ++r) {
                int row = bm * 128 + wm * 64 + m * 16 + lg * 4 + r;
                float val = acc[m][n][r] + bv;
                if (MODE == 0) {
                    ((short*)Cout)[(size_t)row * 1024 + col] = f2b(val);
                } else if (MODE == 1) {
                    int rr = (row >> 11) * 2176 + (row & 2047);
                    ((short*)Cout)[(size_t)rr * 1024 + col] = f2b(val);
                } else {
                    ((float*)Cout)[(size_t)row * 1024 + col] = val;
                }
            }
        }
    }
}

// same core but A already bf16 (output projection reading aout)
template <int MODE>
__device__ __forceinline__ void gemm_core_bf(const short* __restrict__ A,
                                             const short* __restrict__ Bw,
                                             const float* __restrict__ bias,
                                             void* __restrict__ Cout,
                                             int bm, int bn,
                                             short (*As)[32], short (*Bs)[32]) {
    const int tid = threadIdx.x;
    const int w = tid >> 6, lane = tid & 63;
    const int wm = w >> 2, wn = w & 3;
    const int lr = lane & 15, lg = lane >> 4;
    const int srow = tid >> 2;
    const int c_src = (tid & 3) ^ ((tid >> 3) & 3);
    const int w16 = w * 16;
    const int slot = lg ^ ((lr >> 1) & 3);

    const short* Ab = A + (size_t)(bm * 128) * 1024;
    const short* Bb = Bw + (size_t)(bn * 128) * 1024;

    f32x4 acc[4][2] = {};

    for (int k0 = 0; k0 < 1024; k0 += 32) {
        __syncthreads();
        gload16(Ab + (size_t)srow * 1024 + k0 + c_src * 8, &As[w16][0]);
        gload16(Bb + (size_t)srow * 1024 + k0 + c_src * 8, &Bs[w16][0]);
        __syncthreads();
        bf16x8 af[4], bfr[2];
        #pragma unroll
        for (int m = 0; m < 4; ++m) {
            int row = wm * 64 + m * 16 + lr;
            af[m] = *(const bf16x8*)((const char*)As + row * 64 + slot * 16);
        }
        #pragma unroll
        for (int n = 0; n < 2; ++n) {
            int row = wn * 32 + n * 16 + lr;
            bfr[n] = *(const bf16x8*)((const char*)Bs + row * 64 + slot * 16);
        }
        #pragma unroll
        for (int m = 0; m < 4; ++m)
            #pragma unroll
            for (int n = 0; n < 2; ++n)
                acc[m][n] = __builtin_amdgcn_mfma_f32_16x16x32_bf16(af[m], bfr[n], acc[m][n], 0, 0, 0);
    }

    #pragma unroll
    for (int m = 0; m < 4; ++m) {
        #pragma unroll
        for (int n = 0; n < 2; ++n) {
            int col = bn * 128 + wn * 32 + n * 16 + lr;
            float bv = bias[col];
            #pragma unroll
            for (int r = 0; r < 4; ++r) {
                int row = bm * 128 + wm * 64 + m * 16 + lg * 4 + r;
                ((float*)Cout)[(size_t)row * 1024 + col] = acc[m][n][r] + bv;
            }
        }
    }
}

__global__ __launch_bounds__(512) void k_gemm_qkv(const float* __restrict__ q,
                                                  const float* __restrict__ k,
                                                  const float* __restrict__ v,
                                                  const short* __restrict__ Wqb,
                                                  const short* __restrict__ Wkb,
                                                  const short* __restrict__ Wvb,
                                                  const float* __restrict__ bq,
                                                  const float* __restrict__ bk,
                                                  const float* __restrict__ bv,
                                                  short* __restrict__ qp,
                                                  short* __restrict__ kcat,
                                                  short* __restrict__ vcat) {
    __shared__ __align__(16) short As[128][32];
    __shared__ __align__(16) short Bs[128][32];
    const int z = blockIdx.z;
    if (z == 0)      gemm_core<0>(q, Wqb, bq, qp,   blockIdx.x, blockIdx.y, As, Bs);
    else if (z == 1) gemm_core<1>(k, Wkb, bk, kcat, blockIdx.x, blockIdx.y, As, Bs);
    else             gemm_core<1>(v, Wvb, bv, vcat, blockIdx.x, blockIdx.y, As, Bs);
}

__global__ __launch_bounds__(512) void k_gemm_o(const short* __restrict__ aout,
                                                const short* __restrict__ Wob,
                                                const float* __restrict__ bo,
                                                float* __restrict__ out) {
    __shared__ __align__(16) short As[128][32];
    __shared__ __align__(16) short Bs[128][32];
    gemm_core_bf<2>(aout, Wob, bo, out, blockIdx.x, blockIdx.y, As, Bs);
}

// ---------------- per-head V transpose ----------------
__global__ __launch_bounds__(256) void k_vtrans(const short* __restrict__ vcat,
                                                short* __restrict__ vt) {
    __shared__ __align__(16) short t[64][72];
    const int kk0 = blockIdx.x * 64, h = blockIdx.y, b = blockIdx.z;
    const int tid = threadIdx.x;
    const int r = tid >> 3, c = tid & 7;
    #pragma unroll
    for (int i = 0; i < 2; ++i) {
        int row = r + i * 32;
        bf16x8 v = *(const bf16x8*)(vcat + ((size_t)(b * 2176 + kk0 + row)) * 1024 + h * 64 + c * 8);
        *(bf16x8*)(&t[row][c * 8]) = v;
    }
    __syncthreads();
    #pragma unroll
    for (int i = 0; i < 2; ++i) {
        int d = r + i * 32;
        bf16x8 outv;
        #pragma unroll
        for (int j = 0; j < 8; ++j) outv[j] = t[c * 8 + j][d];
        *(bf16x8*)(vt + ((size_t)((b * 16 + h) * 64 + d)) * 2176 + kk0 + c * 8) = outv;
    }
}

// ---------------- flash attention (r14 structure, frozen: 63.7us) ----------------
__global__ __launch_bounds__(512) void k_attn(const short* __restrict__ qp,
                                              const short* __restrict__ kcat,
                                              const short* __restrict__ vt,
                                              const int* __restrict__ maskI,
                                              short* __restrict__ aout) {
    __shared__ __align__(16) short Ks[64][64];
    __shared__ __align__(16) short Vs[64][64];
    __shared__ __align__(16) short Pt[8][16][72];
    __shared__ float smask[2176];

    const int bid = blockIdx.x;
    const int x = bid & 7, j = bid >> 3;
    const int g = x + 8 * (j & 3);   // panel 0..31 (h + 16*b)
    const int qt = j >> 2;           // 0..15
    const int h = g & 15, b = g >> 4;

    const int tid = threadIdx.x;
    const int w = tid >> 6, lane = tid & 63;
    const int lr = lane & 15, lg = lane >> 4;

    for (int i = tid; i < 2176; i += 512) {
        float mval;
        if (i < 2048) mval = maskI[b * 2048 + i] ? -INFINITY : 0.0f;
        else          mval = 0.0f;   // memory slots never masked
        smask[i] = mval;
    }

    const short* Kb = kcat + (size_t)b * 2176 * 1024 + h * 64;
    const short* Vb = vt + ((size_t)(b * 16 + h) * 64) * 2176;

    const int srow8 = lane >> 3;
    const int schunk = (lane & 7) ^ srow8;   // pre-swizzled global 16B chunk

    // Q fragments (16 rows per wave), second-operand layout
    const size_t qbase = ((size_t)(b * 2048 + qt * 128 + w * 16)) * 1024 + h * 64;
    bf16x8 qf[2];
    #pragma unroll
    for (int ks = 0; ks < 2; ++ks)
        qf[ks] = *(const bf16x8*)(qp + qbase + (size_t)lr * 1024 + ks * 32 + lg * 8);

    const float C2 = 0.18033688011f;   // 0.125 * log2(e): softmax in exp2 domain
    float m_run = -1e30f, l_part = 0.0f;
    f32x4 o[4] = {};

    for (int t = 0; t < 33; ++t) {
        const int key0 = t * 64;

        __syncthreads();
        {
            int row = w * 8 + srow8;
            gload16(Kb + (size_t)(key0 + row) * 1024 + schunk * 8, &Ks[w * 8][0]);
            gload16(Vb + (size_t)row * 2176 + key0 + schunk * 8, &Vs[w * 8][0]);
        }
        __syncthreads();

        // S^T = K Q^T : lane holds P[q=lr][key = n*16 + lg*4 + r]
        f32x4 s[4] = {};
        #pragma unroll
        for (int ks = 0; ks < 2; ++ks)
            #pragma unroll
            for (int n = 0; n < 4; ++n) {
                int krow = n * 16 + lr;
                int kchunk = (ks * 4 + lg) ^ (lr & 7);
                bf16x8 kf = *(const bf16x8*)((const char*)(&Ks[0][0]) + krow * 128 + kchunk * 16);
                s[n] = __builtin_amdgcn_mfma_f32_16x16x32_bf16(kf, qf[ks], s[n], 0, 0, 0);
            }

        // scale (exp2 domain) + mask; lane-local partial max
        float lm = -1e30f;
        #pragma unroll
        for (int n = 0; n < 4; ++n) {
            float4 mq = *(const float4*)(&smask[key0 + n * 16 + lg * 4]);
            s[n][0] = fmaf(s[n][0], C2, mq.x);
            s[n][1] = fmaf(s[n][1], C2, mq.y);
            s[n][2] = fmaf(s[n][2], C2, mq.z);
            s[n][3] = fmaf(s[n][3], C2, mq.w);
            lm = fmaxf(lm, fmaxf(fmaxf(s[n][0], s[n][1]), fmaxf(s[n][2], s[n][3])));
        }

        // defer-max (log2 units): rescale only when max grew past m_run + 4
        if (__any(lm - m_run > 4.0f)) {
            float tm = lm;
            tm = fmaxf(tm, __shfl_xor(tm, 16));
            tm = fmaxf(tm, __shfl_xor(tm, 32));   // row max across the 4 lg copies
            float mnew = fmaxf(m_run, tm);
            float corr = fexp2(m_run - mnew);
            m_run = mnew;
            l_part *= corr;
            // broadcast corr from q-domain (q=lr) to o-domain (q=lg*4+r)
            #pragma unroll
            for (int r = 0; r < 4; ++r) {
                float cb = __shfl(corr, 20 * lg + r);
                #pragma unroll
                for (int nO = 0; nO < 4; ++nO) o[nO][r] *= cb;
            }
        }

        // exp2 + per-lane partial sum + packed P -> LDS (wave-private rows)
        #pragma unroll
        for (int n = 0; n < 4; ++n) {
            float p0 = fexp2(s[n][0] - m_run);
            float p1 = fexp2(s[n][1] - m_run);
            float p2 = fexp2(s[n][2] - m_run);
            float p3 = fexp2(s[n][3] - m_run);
            l_part += (p0 + p1) + (p2 + p3);
            unsigned pk[2];
            pk[0] = (unsigned)(unsigned short)f2b(p0) | ((unsigned)(unsigned short)f2b(p1) << 16);
            pk[1] = (unsigned)(unsigned short)f2b(p2) | ((unsigned)(unsigned short)f2b(p3) << 16);
            __builtin_memcpy((char*)(&Pt[w][0][0]) + lr * 144 + n * 32 + lg * 8, pk, 8);
        }

        // O += P V  (memcpy-read of Pt: compiler orders vs the memcpy-writes)
        #pragma unroll
        for (int ks2 = 0; ks2 < 2; ++ks2) {
            bf16x8 pa;
            __builtin_memcpy(&pa, (const char*)(&Pt[w][0][0]) + lr * 144 + ks2 * 64 + lg * 16, 16);
            #pragma unroll
            for (int nO = 0; nO < 4; ++nO) {
                int vrow = nO * 16 + lr;
                int vchunk = (ks2 * 4 + lg) ^ (lr & 7);
                bf16x8 vf = *(const bf16x8*)((const char*)(&Vs[0][0]) + vrow * 128 + vchunk * 16);
                o[nO] = __builtin_amdgcn_mfma_f32_16x16x32_bf16(pa, vf, o[nO], 0, 0, 0);
            }
        }
    }

    // final row-sum reduce (lg dim), normalize, store
    float l = l_part;
    l += __shfl_xor(l, 16);
    l += __shfl_xor(l, 32);
    float inv = 1.0f / l;
    #pragma unroll
    for (int r = 0; r < 4; ++r) {
        float ib = __shfl(inv, 20 * lg + r);
        int qrow = qt * 128 + w * 16 + lg * 4 + r;
        #pragma unroll
        for (int nO = 0; nO < 4; ++nO)
            aout[((size_t)(b * 2048 + qrow)) * 1024 + h * 64 + nO * 16 + lr] =
                f2b(o[nO][r] * ib);
    }
}

extern "C" void kernel_launch(void* const* d_in, const int* in_sizes, int n_in,
                              void* d_out, int out_size, void* d_ws, size_t ws_size,
                              hipStream_t stream) {
    const float* q  = (const float*)d_in[0];
    const float* k  = (const float*)d_in[1];
    const float* v  = (const float*)d_in[2];
    const int* mask = (const int*)d_in[3];
    const float* Wq = (const float*)d_in[4];
    const float* bq = (const float*)d_in[5];
    const float* Wk = (const float*)d_in[6];
    const float* bk = (const float*)d_in[7];
    const float* Wv = (const float*)d_in[8];
    const float* bv = (const float*)d_in[9];
    const float* Wo = (const float*)d_in[10];
    const float* bo = (const float*)d_in[11];
    const float* mk = (const float*)d_in[12];
    const float* mv = (const float*)d_in[13];

    char* ws = (char*)d_ws;
    size_t off = 0;
    auto alloc = [&](size_t bytes) {
        char* p = ws + off;
        off += (bytes + 255) & ~(size_t)255;
        return p;
    };
    // NOTE: Wqb..Wob must stay contiguous in this exact order (k_prep writes
    // them as one flat region starting at Wqb).
    short* Wqb  = (short*)alloc(1024ull * 1024 * 2);
    short* Wkb  = (short*)alloc(1024ull * 1024 * 2);
    short* Wvb  = (short*)alloc(1024ull * 1024 * 2);
    short* Wob  = (short*)alloc(1024ull * 1024 * 2);
    short* qp   = (short*)alloc(4096ull * 1024 * 2);
    short* kcat = (short*)alloc(2ull * 2176 * 1024 * 2);
    short* vcat = (short*)alloc(2ull * 2176 * 1024 * 2);
    short* vtb  = (short*)alloc(2ull * 16 * 64 * 2176 * 2);
    short* aout = (short*)alloc(4096ull * 1024 * 2);

    k_prep<<<dim3(1024, 5), 256, 0, stream>>>(Wq, Wk, Wv, Wo, mk, mv,
                                              Wqb, kcat, vcat, vtb);

    k_gemm_qkv<<<dim3(32, 8, 3), 512, 0, stream>>>(q, k, v, Wqb, Wkb, Wvb,
                                                   bq, bk, bv, qp, kcat, vcat);

    k_vtrans<<<dim3(33, 16, 2), 256, 0, stream>>>(vcat, vtb);

    k_attn<<<512, 512, 0, stream>>>(qp, kcat, vtb, mask, aout);

    k_gemm_o<<<dim3(32, 8), 512, 0, stream>>>(aout, Wob, bo, (float*)d_out);
}

// Round 17
// 133.094 us; speedup vs baseline: 1.0967x; 1.0967x over previous
//
#include <hip/hip_runtime.h>
#include <hip/hip_bf16.h>

typedef __attribute__((ext_vector_type(8))) short bf16x8;
typedef __attribute__((ext_vector_type(4))) float f32x4;

__device__ __forceinline__ short f2b(float x) {
    __hip_bfloat16 h = __float2bfloat16(x);
    short s;
    __builtin_memcpy(&s, &h, 2);
    return s;
}

__device__ __forceinline__ void gload16(const short* g, const short* l) {
    __builtin_amdgcn_global_load_lds((const __attribute__((address_space(1))) void*)g,
                                     (__attribute__((address_space(3))) void*)l, 16, 0, 0);
}

// raw 2^x: v_exp_f32 with no libm fixups (r12: exp2f() libm slow path cost 13us).
__device__ __forceinline__ float fexp2(float x) {
#if __has_builtin(__builtin_amdgcn_exp2f)
    return __builtin_amdgcn_exp2f(x);
#else
    return __expf(x * 0.69314718056f);
#endif
}

// ---------------- prep: W fp32->bf16 converts + memory rows/pads ----------------
// q/k/v conversion is FUSED into k_gemm_qkv (r15): saves the 75MB round-trip.
__global__ __launch_bounds__(256) void k_prep(const float* __restrict__ Wq,
                                              const float* __restrict__ Wk,
                                              const float* __restrict__ Wv,
                                              const float* __restrict__ Wo,
                                              const float* __restrict__ mk,
                                              const float* __restrict__ mv,
                                              short* __restrict__ dst,    // = Wqb (base of W bf16 region)
                                              short* __restrict__ kcat,
                                              short* __restrict__ vcat,
                                              short* __restrict__ vt) {
    const int y = blockIdx.y;
    const int i0 = blockIdx.x * 256 + threadIdx.x;
    if (y < 4) {
        const float* src = (y == 0) ? Wq : (y == 1) ? Wk : (y == 2) ? Wv : Wo;
        float4 val = ((const float4*)src)[i0];
        short4 o;
        o.x = f2b(val.x); o.y = f2b(val.y); o.z = f2b(val.z); o.w = f2b(val.w);
        ((short4*)dst)[(size_t)y * 262144 + i0] = o;
    } else {
        if (i0 < 131072) {
            int b = i0 >> 16;
            int r = (i0 >> 10) & 63;
            int d = i0 & 1023;
            kcat[((size_t)(b * 2176 + 2048 + r)) * 1024 + d] = f2b(mk[r * 1024 + d] * 8.0f);
            vcat[((size_t)(b * 2176 + 2048 + r)) * 1024 + d] = f2b(mv[r * 1024 + d] * 8.0f);
            kcat[((size_t)(b * 2176 + 2112 + r)) * 1024 + d] = 0;
            int h = (i0 >> 12) & 15, dd = (i0 >> 6) & 63, c = i0 & 63;
            vt[((size_t)((b * 16 + h) * 64 + dd)) * 2176 + 2112 + c] = 0;
        }
    }
}

// ---------------- bf16 NT GEMM core, A read as FP32 with in-staging convert ----------
// 512 threads / 8 waves (2M x 4N), 128x128 tile, BK=32. (r15 placement: r16's
// register-prefetch variant regressed — __syncthreads drains vmcnt(0), so the
// prefetch only extended live ranges without hiding latency.)
template <int MODE>
__device__ __forceinline__ void gemm_core(const float* __restrict__ A32,
                                          const short* __restrict__ Bw,
                                          const float* __restrict__ bias,
                                          void* __restrict__ Cout,
                                          int bm, int bn,
                                          short (*As)[32], short (*Bs)[32]) {
    const int tid = threadIdx.x;
    const int w = tid >> 6, lane = tid & 63;
    const int wm = w >> 2, wn = w & 3;           // 2 x 4 wave grid
    const int lr = lane & 15, lg = lane >> 4;
    const int srow = tid >> 2;                    // staging row 0..127
    const int c_src = (tid & 3) ^ ((tid >> 3) & 3);
    const int w16 = w * 16;                       // wave-uniform LDS segment base (B)
    const int slot = lg ^ ((lr >> 1) & 3);

    const float* Ab = A32 + (size_t)(bm * 128) * 1024;
    const short* Bb = Bw + (size_t)(bn * 128) * 1024;

    f32x4 acc[4][2] = {};

    for (int k0 = 0; k0 < 1024; k0 += 32) {
        __syncthreads();
        // A: fp32 -> regs -> bf16 -> LDS (slot = tid&3, linear)
        const float* ap = Ab + (size_t)srow * 1024 + k0 + c_src * 8;
        float4 a0 = *(const float4*)ap;
        float4 a1 = *(const float4*)(ap + 4);
        // B: async direct-to-LDS
        gload16(Bb + (size_t)srow * 1024 + k0 + c_src * 8, &Bs[w16][0]);
        bf16x8 apk;
        apk[0] = f2b(a0.x); apk[1] = f2b(a0.y); apk[2] = f2b(a0.z); apk[3] = f2b(a0.w);
        apk[4] = f2b(a1.x); apk[5] = f2b(a1.y); apk[6] = f2b(a1.z); apk[7] = f2b(a1.w);
        *(bf16x8*)((char*)&As[0][0] + srow * 64 + (tid & 3) * 16) = apk;
        __syncthreads();
        bf16x8 af[4], bfr[2];
        #pragma unroll
        for (int m = 0; m < 4; ++m) {
            int row = wm * 64 + m * 16 + lr;
            af[m] = *(const bf16x8*)((const char*)As + row * 64 + slot * 16);
        }
        #pragma unroll
        for (int n = 0; n < 2; ++n) {
            int row = wn * 32 + n * 16 + lr;
            bfr[n] = *(const bf16x8*)((const char*)Bs + row * 64 + slot * 16);
        }
        #pragma unroll
        for (int m = 0; m < 4; ++m)
            #pragma unroll
            for (int n = 0; n < 2; ++n)
                acc[m][n] = __builtin_amdgcn_mfma_f32_16x16x32_bf16(af[m], bfr[n], acc[m][n], 0, 0, 0);
    }

    #pragma unroll
    for (int m = 0; m < 4; ++m) {
        #pragma unroll
        for (int n = 0; n < 2; ++n) {
            int col = bn * 128 + wn * 32 + n * 16 + lr;
            float bv = bias[col];
            #pragma unroll
            for (int r = 0; r < 4; ++r) {
                int row = bm * 128 + wm * 64 + m * 16 + lg * 4 + r;
                float val = acc[m][n][r] + bv;
                if (MODE == 0) {
                    ((short*)Cout)[(size_t)row * 1024 + col] = f2b(val);
                } else if (MODE == 1) {
                    int rr = (row >> 11) * 2176 + (row & 2047);
                    ((short*)Cout)[(size_t)rr * 1024 + col] = f2b(val);
                } else {
                    ((float*)Cout)[(size_t)row * 1024 + col] = val;
                }
            }
        }
    }
}

// same core but A already bf16 (for the output projection reading aout)
template <int MODE>
__device__ __forceinline__ void gemm_core_bf(const short* __restrict__ A,
                                             const short* __restrict__ Bw,
                                             const float* __restrict__ bias,
                                             void* __restrict__ Cout,
                                             int bm, int bn,
                                             short (*As)[32], short (*Bs)[32]) {
    const int tid = threadIdx.x;
    const int w = tid >> 6, lane = tid & 63;
    const int wm = w >> 2, wn = w & 3;
    const int lr = lane & 15, lg = lane >> 4;
    const int srow = tid >> 2;
    const int c_src = (tid & 3) ^ ((tid >> 3) & 3);
    const int w16 = w * 16;
    const int slot = lg ^ ((lr >> 1) & 3);

    const short* Ab = A + (size_t)(bm * 128) * 1024;
    const short* Bb = Bw + (size_t)(bn * 128) * 1024;

    f32x4 acc[4][2] = {};

    for (int k0 = 0; k0 < 1024; k0 += 32) {
        __syncthreads();
        gload16(Ab + (size_t)srow * 1024 + k0 + c_src * 8, &As[w16][0]);
        gload16(Bb + (size_t)srow * 1024 + k0 + c_src * 8, &Bs[w16][0]);
        __syncthreads();
        bf16x8 af[4], bfr[2];
        #pragma unroll
        for (int m = 0; m < 4; ++m) {
            int row = wm * 64 + m * 16 + lr;
            af[m] = *(const bf16x8*)((const char*)As + row * 64 + slot * 16);
        }
        #pragma unroll
        for (int n = 0; n < 2; ++n) {
            int row = wn * 32 + n * 16 + lr;
            bfr[n] = *(const bf16x8*)((const char*)Bs + row * 64 + slot * 16);
        }
        #pragma unroll
        for (int m = 0; m < 4; ++m)
            #pragma unroll
            for (int n = 0; n < 2; ++n)
                acc[m][n] = __builtin_amdgcn_mfma_f32_16x16x32_bf16(af[m], bfr[n], acc[m][n], 0, 0, 0);
    }

    #pragma unroll
    for (int m = 0; m < 4; ++m) {
        #pragma unroll
        for (int n = 0; n < 2; ++n) {
            int col = bn * 128 + wn * 32 + n * 16 + lr;
            float bv = bias[col];
            #pragma unroll
            for (int r = 0; r < 4; ++r) {
                int row = bm * 128 + wm * 64 + m * 16 + lg * 4 + r;
                ((float*)Cout)[(size_t)row * 1024 + col] = acc[m][n][r] + bv;
            }
        }
    }
}

__global__ __launch_bounds__(512) void k_gemm_qkv(const float* __restrict__ q,
                                                  const float* __restrict__ k,
                                                  const float* __restrict__ v,
                                                  const short* __restrict__ Wqb,
                                                  const short* __restrict__ Wkb,
                                                  const short* __restrict__ Wvb,
                                                  const float* __restrict__ bq,
                                                  const float* __restrict__ bk,
                                                  const float* __restrict__ bv,
                                                  short* __restrict__ qp,
                                                  short* __restrict__ kcat,
                                                  short* __restrict__ vcat) {
    __shared__ __align__(16) short As[128][32];
    __shared__ __align__(16) short Bs[128][32];
    const int z = blockIdx.z;
    if (z == 0)      gemm_core<0>(q, Wqb, bq, qp,   blockIdx.x, blockIdx.y, As, Bs);
    else if (z == 1) gemm_core<1>(k, Wkb, bk, kcat, blockIdx.x, blockIdx.y, As, Bs);
    else             gemm_core<1>(v, Wvb, bv, vcat, blockIdx.x, blockIdx.y, As, Bs);
}

__global__ __launch_bounds__(512) void k_gemm_o(const short* __restrict__ aout,
                                                const short* __restrict__ Wob,
                                                const float* __restrict__ bo,
                                                float* __restrict__ out) {
    __shared__ __align__(16) short As[128][32];
    __shared__ __align__(16) short Bs[128][32];
    gemm_core_bf<2>(aout, Wob, bo, out, blockIdx.x, blockIdx.y, As, Bs);
}

// ---------------- per-head V transpose ----------------
__global__ __launch_bounds__(256) void k_vtrans(const short* __restrict__ vcat,
                                                short* __restrict__ vt) {
    __shared__ __align__(16) short t[64][72];
    const int kk0 = blockIdx.x * 64, h = blockIdx.y, b = blockIdx.z;
    const int tid = threadIdx.x;
    const int r = tid >> 3, c = tid & 7;
    #pragma unroll
    for (int i = 0; i < 2; ++i) {
        int row = r + i * 32;
        bf16x8 v = *(const bf16x8*)(vcat + ((size_t)(b * 2176 + kk0 + row)) * 1024 + h * 64 + c * 8);
        *(bf16x8*)(&t[row][c * 8]) = v;
    }
    __syncthreads();
    #pragma unroll
    for (int i = 0; i < 2; ++i) {
        int d = r + i * 32;
        bf16x8 outv;
        #pragma unroll
        for (int j = 0; j < 8; ++j) outv[j] = t[c * 8 + j][d];
        *(bf16x8*)(vt + ((size_t)((b * 16 + h) * 64 + d)) * 2176 + kk0 + c * 8) = outv;
    }
}

// ---------------- flash attention (r14 structure, frozen: 63.7us) ----------------
__global__ __launch_bounds__(512) void k_attn(const short* __restrict__ qp,
                                              const short* __restrict__ kcat,
                                              const short* __restrict__ vt,
                                              const int* __restrict__ maskI,
                                              short* __restrict__ aout) {
    __shared__ __align__(16) short Ks[64][64];
    __shared__ __align__(16) short Vs[64][64];
    __shared__ __align__(16) short Pt[8][16][72];
    __shared__ float smask[2176];

    const int bid = blockIdx.x;
    const int x = bid & 7, j = bid >> 3;
    const int g = x + 8 * (j & 3);   // panel 0..31 (h + 16*b)
    const int qt = j >> 2;           // 0..15
    const int h = g & 15, b = g >> 4;

    const int tid = threadIdx.x;
    const int w = tid >> 6, lane = tid & 63;
    const int lr = lane & 15, lg = lane >> 4;

    for (int i = tid; i < 2176; i += 512) {
        float mval;
        if (i < 2048) mval = maskI[b * 2048 + i] ? -INFINITY : 0.0f;
        else          mval = 0.0f;   // memory slots never masked
        smask[i] = mval;
    }

    const short* Kb = kcat + (size_t)b * 2176 * 1024 + h * 64;
    const short* Vb = vt + ((size_t)(b * 16 + h) * 64) * 2176;

    const int srow8 = lane >> 3;
    const int schunk = (lane & 7) ^ srow8;   // pre-swizzled global 16B chunk

    // Q fragments (16 rows per wave), second-operand layout
    const size_t qbase = ((size_t)(b * 2048 + qt * 128 + w * 16)) * 1024 + h * 64;
    bf16x8 qf[2];
    #pragma unroll
    for (int ks = 0; ks < 2; ++ks)
        qf[ks] = *(const bf16x8*)(qp + qbase + (size_t)lr * 1024 + ks * 32 + lg * 8);

    const float C2 = 0.18033688011f;   // 0.125 * log2(e): softmax in exp2 domain
    float m_run = -1e30f, l_part = 0.0f;
    f32x4 o[4] = {};

    for (int t = 0; t < 33; ++t) {
        const int key0 = t * 64;

        __syncthreads();
        {
            int row = w * 8 + srow8;
            gload16(Kb + (size_t)(key0 + row) * 1024 + schunk * 8, &Ks[w * 8][0]);
            gload16(Vb + (size_t)row * 2176 + key0 + schunk * 8, &Vs[w * 8][0]);
        }
        __syncthreads();

        // S^T = K Q^T : lane holds P[q=lr][key = n*16 + lg*4 + r]
        f32x4 s[4] = {};
        #pragma unroll
        for (int ks = 0; ks < 2; ++ks)
            #pragma unroll
            for (int n = 0; n < 4; ++n) {
                int krow = n * 16 + lr;
                int kchunk = (ks * 4 + lg) ^ (lr & 7);
                bf16x8 kf = *(const bf16x8*)((const char*)(&Ks[0][0]) + krow * 128 + kchunk * 16);
                s[n] = __builtin_amdgcn_mfma_f32_16x16x32_bf16(kf, qf[ks], s[n], 0, 0, 0);
            }

        // scale (exp2 domain) + mask; lane-local partial max
        float lm = -1e30f;
        #pragma unroll
        for (int n = 0; n < 4; ++n) {
            float4 mq = *(const float4*)(&smask[key0 + n * 16 + lg * 4]);
            s[n][0] = fmaf(s[n][0], C2, mq.x);
            s[n][1] = fmaf(s[n][1], C2, mq.y);
            s[n][2] = fmaf(s[n][2], C2, mq.z);
            s[n][3] = fmaf(s[n][3], C2, mq.w);
            lm = fmaxf(lm, fmaxf(fmaxf(s[n][0], s[n][1]), fmaxf(s[n][2], s[n][3])));
        }

        // defer-max (log2 units): rescale only when max grew past m_run + 4
        if (__any(lm - m_run > 4.0f)) {
            float tm = lm;
            tm = fmaxf(tm, __shfl_xor(tm, 16));
            tm = fmaxf(tm, __shfl_xor(tm, 32));   // row max across the 4 lg copies
            float mnew = fmaxf(m_run, tm);
            float corr = fexp2(m_run - mnew);
            m_run = mnew;
            l_part *= corr;
            // broadcast corr from q-domain (q=lr) to o-domain (q=lg*4+r)
            #pragma unroll
            for (int r = 0; r < 4; ++r) {
                float cb = __shfl(corr, 20 * lg + r);
                #pragma unroll
                for (int nO = 0; nO < 4; ++nO) o[nO][r] *= cb;
            }
        }

        // exp2 + per-lane partial sum + packed P -> LDS (wave-private rows)
        #pragma unroll
        for (int n = 0; n < 4; ++n) {
            float p0 = fexp2(s[n][0] - m_run);
            float p1 = fexp2(s[n][1] - m_run);
            float p2 = fexp2(s[n][2] - m_run);
            float p3 = fexp2(s[n][3] - m_run);
            l_part += (p0 + p1) + (p2 + p3);
            unsigned pk[2];
            pk[0] = (unsigned)(unsigned short)f2b(p0) | ((unsigned)(unsigned short)f2b(p1) << 16);
            pk[1] = (unsigned)(unsigned short)f2b(p2) | ((unsigned)(unsigned short)f2b(p3) << 16);
            __builtin_memcpy((char*)(&Pt[w][0][0]) + lr * 144 + n * 32 + lg * 8, pk, 8);
        }

        // O += P V  (memcpy-read of Pt: compiler orders vs the memcpy-writes)
        #pragma unroll
        for (int ks2 = 0; ks2 < 2; ++ks2) {
            bf16x8 pa;
            __builtin_memcpy(&pa, (const char*)(&Pt[w][0][0]) + lr * 144 + ks2 * 64 + lg * 16, 16);
            #pragma unroll
            for (int nO = 0; nO < 4; ++nO) {
                int vrow = nO * 16 + lr;
                int vchunk = (ks2 * 4 + lg) ^ (lr & 7);
                bf16x8 vf = *(const bf16x8*)((const char*)(&Vs[0][0]) + vrow * 128 + vchunk * 16);
                o[nO] = __builtin_amdgcn_mfma_f32_16x16x32_bf16(pa, vf, o[nO], 0, 0, 0);
            }
        }
    }

    // final row-sum reduce (lg dim), normalize, store
    float l = l_part;
    l += __shfl_xor(l, 16);
    l += __shfl_xor(l, 32);
    float inv = 1.0f / l;
    #pragma unroll
    for (int r = 0; r < 4; ++r) {
        float ib = __shfl(inv, 20 * lg + r);
        int qrow = qt * 128 + w * 16 + lg * 4 + r;
        #pragma unroll
        for (int nO = 0; nO < 4; ++nO)
            aout[((size_t)(b * 2048 + qrow)) * 1024 + h * 64 + nO * 16 + lr] =
                f2b(o[nO][r] * ib);
    }
}

extern "C" void kernel_launch(void* const* d_in, const int* in_sizes, int n_in,
                              void* d_out, int out_size, void* d_ws, size_t ws_size,
                              hipStream_t stream) {
    const float* q  = (const float*)d_in[0];
    const float* k  = (const float*)d_in[1];
    const float* v  = (const float*)d_in[2];
    const int* mask = (const int*)d_in[3];
    const float* Wq = (const float*)d_in[4];
    const float* bq = (const float*)d_in[5];
    const float* Wk = (const float*)d_in[6];
    const float* bk = (const float*)d_in[7];
    const float* Wv = (const float*)d_in[8];
    const float* bv = (const float*)d_in[9];
    const float* Wo = (const float*)d_in[10];
    const float* bo = (const float*)d_in[11];
    const float* mk = (const float*)d_in[12];
    const float* mv = (const float*)d_in[13];

    char* ws = (char*)d_ws;
    size_t off = 0;
    auto alloc = [&](size_t bytes) {
        char* p = ws + off;
        off += (bytes + 255) & ~(size_t)255;
        return p;
    };
    // NOTE: Wqb..Wob must stay contiguous in this exact order (k_prep writes
    // them as one flat region starting at Wqb).
    short* Wqb  = (short*)alloc(1024ull * 1024 * 2);
    short* Wkb  = (short*)alloc(1024ull * 1024 * 2);
    short* Wvb  = (short*)alloc(1024ull * 1024 * 2);
    short* Wob  = (short*)alloc(1024ull * 1024 * 2);
    short* qp   = (short*)alloc(4096ull * 1024 * 2);
    short* kcat = (short*)alloc(2ull * 2176 * 1024 * 2);
    short* vcat = (short*)alloc(2ull * 2176 * 1024 * 2);
    short* vtb  = (short*)alloc(2ull * 16 * 64 * 2176 * 2);
    short* aout = (short*)alloc(4096ull * 1024 * 2);

    k_prep<<<dim3(1024, 5), 256, 0, stream>>>(Wq, Wk, Wv, Wo, mk, mv,
                                              Wqb, kcat, vcat, vtb);

    k_gemm_qkv<<<dim3(32, 8, 3), 512, 0, stream>>>(q, k, v, Wqb, Wkb, Wvb,
                                                   bq, bk, bv, qp, kcat, vcat);

    k_vtrans<<<dim3(33, 16, 2), 256, 0, stream>>>(vcat, vtb);

    k_attn<<<512, 512, 0, stream>>>(qp, kcat, vtb, mask, aout);

    k_gemm_o<<<dim3(32, 8), 512, 0, stream>>>(aout, Wob, bo, (float*)d_out);
}